// Round 5
// baseline (574.685 us; speedup 1.0000x reference)
//
#include <hip/hip_runtime.h>

#define BD 8
#define CD 128
#define HD 96
#define WD 96
#define PD 9216      // H*W
#define ND 73728     // B*P

typedef __attribute__((ext_vector_type(8))) short short8;
typedef __attribute__((ext_vector_type(4))) float f32x4;

__device__ inline float bfu2f(unsigned int u) { return __uint_as_float(u << 16); }
__device__ inline unsigned short f2bfu(float f) {
  unsigned int u = __float_as_uint(f);
  u += 0x7fffu + ((u >> 16) & 1u);   // RNE
  return (unsigned short)(u >> 16);
}

template<bool F32>
__device__ __forceinline__ float ldv(const void* __restrict__ p, size_t i) {
  if constexpr (F32) return ((const float*)p)[i];
  else return bfu2f(((const unsigned short*)p)[i]);
}

// ---------------- storage-dtype detector ----------------
// Case A: f32 storage of bf16-quantized values -> low 16 bits of ~every word are 0.
// Case B: f32 storage, full precision -> ~0.4% of low halfwords have exp 0xFF.
// Case C: true bf16 storage -> neither (bf16 of N(0,1) is never exp-0xFF, never exactly 0).
__global__ void k_detect(const unsigned int* __restrict__ xw, int* __restrict__ flag) {
  __shared__ int lz, e255;
  if (threadIdx.x == 0) { lz = 0; e255 = 0; }
  __syncthreads();
  int mylz = 0, my255 = 0;
  for (int i = threadIdx.x; i < 65536; i += 256) {
    unsigned int w = xw[i];
    if ((w & 0xFFFFu) == 0u) mylz++;
    if (((w >> 7) & 0xFFu) == 0xFFu) my255++;
  }
  atomicAdd(&lz, mylz);
  atomicAdd(&e255, my255);
  __syncthreads();
  if (threadIdx.x == 0) *flag = (lz > 4096 || e255 > 0) ? 1 : 0;  // 1 = float32 storage
}

__global__ void k_init(unsigned long long* dmm) {
  int t = threadIdx.x;
  if (t < 8) dmm[t] = 0x7FEFFFFFFFFFFFFFULL;  // DBL_MAX bits (min slots)
  else if (t < 16) dmm[t] = 0ULL;             // max slots
}

// ---------------- canonical bf16 weights for MFMA B-operands ----------------
__global__ void k_cvtw(const void* __restrict__ w1, const void* __restrict__ w2,
                       unsigned short* __restrict__ wc, const int* __restrict__ flag) {
  bool f32 = (*flag != 0);
  int t = blockIdx.x * 256 + threadIdx.x;   // 0..65535
  if (t < 32768)
    wc[t] = f32 ? f2bfu(((const float*)w1)[t]) : ((const unsigned short*)w1)[t];
  else {
    int u = t - 32768;
    wc[t] = f32 ? f2bfu(((const float*)w2)[u]) : ((const unsigned short*)w2)[u];
  }
}

// ---------------- per-pixel channel mean + L2 norm (fp64) ----------------
template<bool F32>
__device__ __forceinline__ void stats_body(const void* __restrict__ x,
                                           double* __restrict__ avg, double* __restrict__ nrm,
                                           int gp) {
  int b = gp / PD, p = gp - b * PD;
  size_t base = (size_t)b * CD * PD + p;
  double s = 0.0, q = 0.0;
  for (int c = 0; c < CD; ++c) {
    float v = ldv<F32>(x, base + (size_t)c * PD);
    s += (double)v;
    q += (double)v * (double)v;
  }
  avg[gp] = s * (1.0 / 128.0);
  nrm[gp] = sqrt(q);
}
__global__ void k_stats(const void* __restrict__ x, const int* __restrict__ flag,
                        double* __restrict__ avg, double* __restrict__ nrm) {
  int gp = blockIdx.x * 256 + threadIdx.x;
  if (*flag) stats_body<true>(x, avg, nrm, gp);
  else stats_body<false>(x, avg, nrm, gp);
}

// zero-padded Laplacian on the mean map
__device__ inline double lap_df(const double* __restrict__ a, int b, int y, int x) {
  const double* ab = a + (size_t)b * PD;
  double v = 4.0 * ab[y * WD + x];
  if (y > 0)      v -= ab[(y - 1) * WD + x];
  if (y < HD - 1) v -= ab[(y + 1) * WD + x];
  if (x > 0)      v -= ab[y * WD + x - 1];
  if (x < WD - 1) v -= ab[y * WD + x + 1];
  return fabs(v);
}

// ---------------- per-batch min/max of df ----------------
__global__ void k_minmax(const double* __restrict__ avg, unsigned long long* __restrict__ dmm) {
  __shared__ double mnL[256], mxL[256];
  int t = threadIdx.x;
  int gp = blockIdx.x * 256 + t;            // 256 | PD -> block never crosses batch
  int b = gp / PD, p = gp - b * PD;
  double df = lap_df(avg, b, p / WD, p % WD);
  mnL[t] = df; mxL[t] = df;
  __syncthreads();
  if (t == 0) {
    double mn = mnL[0], mx = mxL[0];
    for (int i = 1; i < 256; ++i) { mn = fmin(mn, mnL[i]); mx = fmax(mx, mxL[i]); }
    atomicMin(&dmm[b], (unsigned long long)__double_as_longlong(mn));
    atomicMax(&dmm[b + 8], (unsigned long long)__double_as_longlong(mx));
  }
}

// ---------------- GroupNorm stats ----------------
template<bool F32>
__device__ __forceinline__ void gn_body(const void* __restrict__ x, float* __restrict__ gn,
                                        double* sS, double* sQ, int bg) {
  size_t base = (size_t)bg * 8 * PD;   // 73728 elements per (b,g)
  int t = threadIdx.x;
  double s = 0.0, q = 0.0;
  for (int i = t; i < 73728; i += 256) {
    float v = ldv<F32>(x, base + i);
    s += (double)v;
    q += (double)v * (double)v;
  }
  sS[t] = s; sQ[t] = q;
  __syncthreads();
  if (t == 0) {
    double S = 0.0, Q = 0.0;
    for (int i = 0; i < 256; ++i) { S += sS[i]; Q += sQ[i]; }
    double mu = S / 73728.0;
    double var = Q / 73728.0 - mu * mu;
    gn[bg] = (float)mu;
    gn[128 + bg] = (float)(1.0 / sqrt(var + 1e-5));
  }
}
__global__ void k_gn(const void* __restrict__ x, const int* __restrict__ flag,
                     float* __restrict__ gn) {
  __shared__ double sS[256], sQ[256];
  if (*flag) gn_body<true>(x, gn, sS, sQ, blockIdx.x);
  else gn_body<false>(x, gn, sS, sQ, blockIdx.x);
}

// reflect neighbor table for pixel p (y,x)
__device__ __forceinline__ void neigh9(int y, int xx, int* q) {
  #pragma unroll
  for (int dy = 0; dy < 3; ++dy) {
    int yy = y + dy - 1;
    yy = yy < 0 ? -yy : (yy >= HD ? 2 * HD - 2 - yy : yy);
    #pragma unroll
    for (int dx = 0; dx < 3; ++dx) {
      int xr = xx + dx - 1;
      xr = xr < 0 ? -xr : (xr >= WD ? 2 * WD - 2 - xr : xr);
      q[dy * 3 + dx] = yy * WD + xr;
    }
  }
}

// ---------------- fused IPG + GN + FFN megakernel (f32 output) ----------------
// LDS: union{ sdp[256][9] f64 + wls[64][9] f32 | Hl[64][272] bf16 } + et[64][136] bf16 = 52224 B
template<bool F32>
__device__ __forceinline__ void mega_body(const void* __restrict__ x,
                                          const double* __restrict__ avg,
                                          const double* __restrict__ nrm,
                                          const unsigned long long* __restrict__ dmm,
                                          const float* __restrict__ gn,
                                          const void* __restrict__ gw, const void* __restrict__ gb,
                                          const void* __restrict__ b1, const void* __restrict__ b2,
                                          const unsigned short* __restrict__ wc,
                                          float* __restrict__ outp,
                                          char* __restrict__ un,
                                          unsigned short (*et)[136]) {
  double (*sdp)[9] = (double(*)[9])un;                        // [0, 18432)
  float (*wls)[9] = (float(*)[9])(un + 18432);                // [18432, 20736)
  unsigned short (*Hl)[272] = (unsigned short(*)[272])un;     // phase-2 overlay

  const int t = threadIdx.x;
  const int gp0 = blockIdx.x * 64;          // 64 | PD -> block within one batch
  const int b = gp0 / PD, p0b = gp0 - b * PD;
  const size_t xb = (size_t)b * CD * PD;

  // ---- phase 1a: partial sims, thread = (pixel px, channel quarter qt) ----
  {
    const int px = t & 63, qt = t >> 6;
    const int p = p0b + px;
    int q[9];
    neigh9(p / WD, p % WD, q);
    double sdl[9];
    #pragma unroll
    for (int k = 0; k < 9; ++k) sdl[k] = 0.0;
    for (int c = qt * 32; c < qt * 32 + 32; ++c) {
      size_t xc = xb + (size_t)c * PD;
      double vc = (double)ldv<F32>(x, xc + p);
      #pragma unroll
      for (int k = 0; k < 9; ++k) sdl[k] += vc * (double)ldv<F32>(x, xc + q[k]);
    }
    #pragma unroll
    for (int k = 0; k < 9; ++k) sdp[t][k] = sdl[k];
  }
  __syncthreads();

  // ---- phase 1b: one thread per pixel -> counts, ranks, softmax weights ----
  if (t < 64) {
    const int px = t;
    const int p = p0b + px;
    const int y = p / WD, xx = p - y * WD;
    int q[9];
    neigh9(y, xx, q);
    double dmin = __longlong_as_double((long long)dmm[b]);
    double dmax = __longlong_as_double((long long)dmm[b + 8]);
    double df = lap_df(avg, b, y, xx);
    double dn = (df - dmin) / (dmax - dmin + 1e-8);
    int kk = 1 + (int)rint(dn * 7.0);
    kk = kk < 1 ? 1 : (kk > 8 ? 8 : kk);

    double np_ = fmax(nrm[b * PD + p], 1e-12);
    double s[9];
    #pragma unroll
    for (int k = 0; k < 9; ++k) {
      double sd = sdp[px][k] + sdp[px + 64][k] + sdp[px + 128][k] + sdp[px + 192][k];
      double nq = fmax(nrm[b * PD + q[k]], 1e-12);
      s[k] = sd / (np_ * nq);
    }
    float w[9];
    float wsum = 0.f;
    #pragma unroll
    for (int j = 0; j < 9; ++j) {
      int rank = 0;
      #pragma unroll
      for (int i = 0; i < 9; ++i)
        rank += (s[i] > s[j]) || (s[i] == s[j] && i < j);   // stable tie rule
      w[j] = (rank < kk) ? expf((float)s[j]) : 0.f;
      wsum += w[j];
    }
    float inv = 1.f / wsum;
    #pragma unroll
    for (int j = 0; j < 9; ++j) wls[px][j] = w[j] * inv;
  }
  __syncthreads();

  // ---- phase 1c: aggregate + GroupNorm; ownership matches stage-2 C-layout ----
  // thread owns pixels (wave*16+quad*4+r, r=0..3) x channels (r16+16j, j=0..7)
  const int lane = t & 63, wave = t >> 6;
  const int r16 = lane & 15, quad = lane >> 4;
  float e32[4][8];
  {
    const int g16 = b * 16;
    #pragma unroll
    for (int r = 0; r < 4; ++r) {
      const int px = wave * 16 + quad * 4 + r;
      const int p = p0b + px;
      int q[9];
      neigh9(p / WD, p % WD, q);
      float w[9];
      #pragma unroll
      for (int k = 0; k < 9; ++k) w[k] = wls[px][k];
      #pragma unroll
      for (int j = 0; j < 8; ++j) {
        const int c = r16 + 16 * j;
        size_t xc = xb + (size_t)c * PD;
        float og = 0.f;
        #pragma unroll
        for (int k = 0; k < 9; ++k) og += w[k] * ldv<F32>(x, xc + q[k]);
        float vc = ldv<F32>(x, xc + p);
        int g = c >> 3;
        float e = og + (vc - gn[g16 + g]) * gn[128 + g16 + g] * ldv<F32>(gw, c) + ldv<F32>(gb, c);
        e32[r][j] = e;
        et[px][c] = f2bfu(e);
      }
    }
  }
  __syncthreads();   // et complete; sdp/wls dead -> Hl overlay may be written

  // ---- phase 2 stage 1: H[64x256] = relu(et * W1^T + b1) ----
  const unsigned short* wc1 = wc;          // w1 [256][128]
  const unsigned short* wc2 = wc + 32768;  // w2 [128][256]
  f32x4 acc[16];
  #pragma unroll
  for (int nt = 0; nt < 16; ++nt) acc[nt] = (f32x4){0.f, 0.f, 0.f, 0.f};
  #pragma unroll
  for (int kk = 0; kk < 4; ++kk) {
    short8 af = *(const short8*)&et[wave * 16 + r16][kk * 32 + quad * 8];
    #pragma unroll
    for (int nt = 0; nt < 16; ++nt) {
      const short8* Bp = (const short8*)(wc1 + (size_t)(nt * 16 + r16) * 128 + kk * 32 + quad * 8);
      acc[nt] = __builtin_amdgcn_mfma_f32_16x16x32_bf16(af, *Bp, acc[nt], 0, 0, 0);
    }
  }
  #pragma unroll
  for (int nt = 0; nt < 16; ++nt) {
    int n = nt * 16 + r16;
    float bias = ldv<F32>(b1, n);
    #pragma unroll
    for (int r = 0; r < 4; ++r)
      Hl[wave * 16 + quad * 4 + r][n] = f2bfu(fmaxf(acc[nt][r] + bias, 0.f));
  }
  __syncthreads();

  // ---- phase 2 stage 2: out = H * W2^T + b2 + enhanced (f32 residual in regs) ----
  f32x4 acc2[8];
  #pragma unroll
  for (int nt = 0; nt < 8; ++nt) acc2[nt] = (f32x4){0.f, 0.f, 0.f, 0.f};
  #pragma unroll
  for (int kk = 0; kk < 8; ++kk) {
    short8 af = *(const short8*)&Hl[wave * 16 + r16][kk * 32 + quad * 8];
    #pragma unroll
    for (int nt = 0; nt < 8; ++nt) {
      const short8* Bp = (const short8*)(wc2 + (size_t)(nt * 16 + r16) * 256 + kk * 32 + quad * 8);
      acc2[nt] = __builtin_amdgcn_mfma_f32_16x16x32_bf16(af, *Bp, acc2[nt], 0, 0, 0);
    }
  }
  const int mloc0 = wave * 16 + quad * 4;
  const int pp0 = p0b + mloc0;             // pp0 % 4 == 0
  #pragma unroll
  for (int nt = 0; nt < 8; ++nt) {
    int n = nt * 16 + r16;
    float bias = ldv<F32>(b2, n);
    float4 o;
    o.x = acc2[nt][0] + bias + e32[0][nt];
    o.y = acc2[nt][1] + bias + e32[1][nt];
    o.z = acc2[nt][2] + bias + e32[2][nt];
    o.w = acc2[nt][3] + bias + e32[3][nt];
    *(float4*)(outp + (size_t)(b * CD + n) * PD + pp0) = o;
  }
}

__global__ __launch_bounds__(256, 1) void k_mega(const void* __restrict__ x,
                                                 const int* __restrict__ flag,
                                                 const double* __restrict__ avg,
                                                 const double* __restrict__ nrm,
                                                 const unsigned long long* __restrict__ dmm,
                                                 const float* __restrict__ gn,
                                                 const void* __restrict__ gw,
                                                 const void* __restrict__ gb,
                                                 const void* __restrict__ b1,
                                                 const void* __restrict__ b2,
                                                 const unsigned short* __restrict__ wc,
                                                 float* __restrict__ outp) {
  __shared__ char un[34816];               // union: sdp+wls | Hl
  __shared__ unsigned short et[64][136];   // enh tile (bf16 A-operand), padded stride
  if (*flag) mega_body<true>(x, avg, nrm, dmm, gn, gw, gb, b1, b2, wc, outp, un, et);
  else mega_body<false>(x, avg, nrm, dmm, gn, gw, gb, b1, b2, wc, outp, un, et);
}

extern "C" void kernel_launch(void* const* d_in, const int* in_sizes, int n_in,
                              void* d_out, int out_size, void* d_ws, size_t ws_size,
                              hipStream_t stream) {
  // dict order: x, gn_weight(128), gn_bias(128), w1(32768), b1(256), w2(32768), b2(128)
  const void* x  = d_in[0];
  const void* gw = d_in[1];
  const void* gb = d_in[2];
  const void* w1 = d_in[3];
  const void* b1 = d_in[4];
  const void* w2 = d_in[5];
  const void* b2 = d_in[6];
  float* out = (float*)d_out;

  char* ws = (char*)d_ws;
  int* flag = (int*)ws;                                      // [0,256)
  unsigned long long* dmm = (unsigned long long*)(ws + 256); // [256,512)
  float* gn = (float*)(ws + 512);                            // [512,1536)
  unsigned short* wc = (unsigned short*)(ws + 1536);         // 131072 B -> 132608
  double* avg = (double*)(ws + 132608);                      // 589824 B -> 722432
  double* nrm = (double*)(ws + 722432);                      // 589824 B -> ~1.25 MB

  k_detect<<<1, 256, 0, stream>>>((const unsigned int*)x, flag);
  k_init<<<1, 64, 0, stream>>>(dmm);
  k_cvtw<<<256, 256, 0, stream>>>(w1, w2, wc, flag);
  k_stats<<<ND / 256, 256, 0, stream>>>(x, flag, avg, nrm);
  k_minmax<<<ND / 256, 256, 0, stream>>>(avg, dmm);
  k_gn<<<BD * 16, 256, 0, stream>>>(x, flag, gn);
  k_mega<<<ND / 64, 256, 0, stream>>>(x, flag, avg, nrm, dmm, gn, gw, gb, b1, b2, wc, out);
}

// Round 9
// 442.653 us; speedup vs baseline: 1.2983x; 1.2983x over previous
//
#include <hip/hip_runtime.h>

#define BD 8
#define CD 128
#define HD 96
#define WD 96
#define PD 9216      // H*W
#define ND 73728     // B*P

typedef __attribute__((ext_vector_type(8))) short short8;
typedef __attribute__((ext_vector_type(4))) float f32x4;

__device__ inline float bfu2f(unsigned int u) { return __uint_as_float(u << 16); }
__device__ inline unsigned short f2bfu(float f) {
  unsigned int u = __float_as_uint(f);
  u += 0x7fffu + ((u >> 16) & 1u);   // RNE
  return (unsigned short)(u >> 16);
}

template<bool F32>
__device__ __forceinline__ float ldv(const void* __restrict__ p, size_t i) {
  if constexpr (F32) return ((const float*)p)[i];
  else return bfu2f(((const unsigned short*)p)[i]);
}

// ---------------- R5-exact: storage-dtype detector ----------------
__global__ void k_detect(const unsigned int* __restrict__ xw, int* __restrict__ flag) {
  __shared__ int lz, e255;
  if (threadIdx.x == 0) { lz = 0; e255 = 0; }
  __syncthreads();
  int mylz = 0, my255 = 0;
  for (int i = threadIdx.x; i < 65536; i += 256) {
    unsigned int w = xw[i];
    if ((w & 0xFFFFu) == 0u) mylz++;
    if (((w >> 7) & 0xFFu) == 0xFFu) my255++;
  }
  atomicAdd(&lz, mylz);
  atomicAdd(&e255, my255);
  __syncthreads();
  if (threadIdx.x == 0) *flag = (lz > 4096 || e255 > 0) ? 1 : 0;  // 1 = float32 storage
}

// ---------------- R5-exact: init min/max slots ----------------
__global__ void k_init(unsigned long long* dmm) {
  int t = threadIdx.x;
  if (t < 8) dmm[t] = 0x7FEFFFFFFFFFFFFFULL;  // min slots (DBL_MAX bits)
  else if (t < 16) dmm[t] = 0ULL;             // max slots
}

// ---------------- R5-exact: canonical bf16 weights for MFMA B-operands ----------------
__global__ void k_cvtw(const void* __restrict__ w1, const void* __restrict__ w2,
                       unsigned short* __restrict__ wc, const int* __restrict__ flag) {
  bool f32 = (*flag != 0);
  int t = blockIdx.x * 256 + threadIdx.x;   // 0..65535
  if (t < 32768)
    wc[t] = f32 ? f2bfu(((const float*)w1)[t]) : ((const unsigned short*)w1)[t];
  else {
    int u = t - 32768;
    wc[t] = f32 ? f2bfu(((const float*)w2)[u]) : ((const unsigned short*)w2)[u];
  }
}

// ---------------- R5-exact: per-pixel channel mean + L2 norm (fp64) ----------------
template<bool F32>
__device__ __forceinline__ void stats_body(const void* __restrict__ x,
                                           double* __restrict__ avg, double* __restrict__ nrm,
                                           int gp) {
  int b = gp / PD, p = gp - b * PD;
  size_t base = (size_t)b * CD * PD + p;
  double s = 0.0, q = 0.0;
  for (int c = 0; c < CD; ++c) {
    float v = ldv<F32>(x, base + (size_t)c * PD);
    s += (double)v;
    q += (double)v * (double)v;
  }
  avg[gp] = s * (1.0 / 128.0);
  nrm[gp] = sqrt(q);
}
__global__ void k_stats(const void* __restrict__ x, const int* __restrict__ flag,
                        double* __restrict__ avg, double* __restrict__ nrm) {
  int gp = blockIdx.x * 256 + threadIdx.x;
  if (*flag) stats_body<true>(x, avg, nrm, gp);
  else stats_body<false>(x, avg, nrm, gp);
}

// zero-padded Laplacian on the mean map
__device__ inline double lap_df(const double* __restrict__ a, int b, int y, int x) {
  const double* ab = a + (size_t)b * PD;
  double v = 4.0 * ab[y * WD + x];
  if (y > 0)      v -= ab[(y - 1) * WD + x];
  if (y < HD - 1) v -= ab[(y + 1) * WD + x];
  if (x > 0)      v -= ab[y * WD + x - 1];
  if (x < WD - 1) v -= ab[y * WD + x + 1];
  return fabs(v);
}

// ---------------- R5-exact: per-batch min/max of df (LDS-scalar reduction) ----------------
__global__ void k_minmax(const double* __restrict__ avg, unsigned long long* __restrict__ dmm) {
  __shared__ double mnL[256], mxL[256];
  int t = threadIdx.x;
  int gp = blockIdx.x * 256 + t;            // 256 | PD -> block never crosses batch
  int b = gp / PD, p = gp - b * PD;
  double df = lap_df(avg, b, p / WD, p % WD);
  mnL[t] = df; mxL[t] = df;
  __syncthreads();
  if (t == 0) {
    double mn = mnL[0], mx = mxL[0];
    for (int i = 1; i < 256; ++i) { mn = fmin(mn, mnL[i]); mx = fmax(mx, mxL[i]); }
    atomicMin(&dmm[b], (unsigned long long)__double_as_longlong(mn));
    atomicMax(&dmm[b + 8], (unsigned long long)__double_as_longlong(mx));
  }
}

// ---------------- R5-exact: GroupNorm stats ----------------
template<bool F32>
__device__ __forceinline__ void gn_body(const void* __restrict__ x, float* __restrict__ gn,
                                        double* sS, double* sQ, int bg) {
  size_t base = (size_t)bg * 8 * PD;   // 73728 elements per (b,g)
  int t = threadIdx.x;
  double s = 0.0, q = 0.0;
  for (int i = t; i < 73728; i += 256) {
    float v = ldv<F32>(x, base + i);
    s += (double)v;
    q += (double)v * (double)v;
  }
  sS[t] = s; sQ[t] = q;
  __syncthreads();
  if (t == 0) {
    double S = 0.0, Q = 0.0;
    for (int i = 0; i < 256; ++i) { S += sS[i]; Q += sQ[i]; }
    double mu = S / 73728.0;
    double var = Q / 73728.0 - mu * mu;
    gn[bg] = (float)mu;
    gn[128 + bg] = (float)(1.0 / sqrt(var + 1e-5));
  }
}
__global__ void k_gn(const void* __restrict__ x, const int* __restrict__ flag,
                     float* __restrict__ gn) {
  __shared__ double sS[256], sQ[256];
  if (*flag) gn_body<true>(x, gn, sS, sQ, blockIdx.x);
  else gn_body<false>(x, gn, sS, sQ, blockIdx.x);
}

// ---------------- transpose only: x -> pixel-major FLOAT32 xpm (lossless) ----------------
template<bool F32>
__device__ __forceinline__ void pmt_body(const void* __restrict__ x,
                                         float* __restrict__ xpm, float (*tile)[132]) {
  const int t = threadIdx.x, px = t & 63, ci = t >> 6;
  const int gp0 = blockIdx.x * 64, b = gp0 / PD, p0 = gp0 - b * PD;
  for (int j = 0; j < 32; ++j) {
    int c = ci * 32 + j;
    tile[px][c] = ldv<F32>(x, (size_t)(b * CD + c) * PD + p0 + px);   // coalesced
  }
  __syncthreads();
  for (int i = t; i < 2048; i += 256) {
    int r = i >> 5, seg = i & 31;
    *(float4*)(xpm + (size_t)(gp0 + r) * 128 + seg * 4) = *(const float4*)&tile[r][seg * 4];
  }
}
__global__ __launch_bounds__(256) void k_pmt(const void* __restrict__ x,
                                             const int* __restrict__ flag,
                                             float* __restrict__ xpm) {
  __shared__ float tile[64][132];
  if (*flag) pmt_body<true>(x, xpm, tile);
  else pmt_body<false>(x, xpm, tile);
}

// reflect neighbor table
__device__ __forceinline__ void neigh9(int y, int xx, int* q) {
  #pragma unroll
  for (int dy = 0; dy < 3; ++dy) {
    int yy = y + dy - 1;
    yy = yy < 0 ? -yy : (yy >= HD ? 2 * HD - 2 - yy : yy);
    #pragma unroll
    for (int dx = 0; dx < 3; ++dx) {
      int xr = xx + dx - 1;
      xr = xr < 0 ? -xr : (xr >= WD ? 2 * WD - 2 - xr : xr);
      q[dy * 3 + dx] = yy * WD + xr;
    }
  }
}

// ---------------- fused IPG + GN + FFN: R5-exact math, f32 vector loads ----------------
// LDS: union{ sdp[256][9] f64 + wls[64][9] f32 | Hl[64][272] bf16 } + et[64][136] = 52224 B
template<bool F32>
__device__ __forceinline__ void fused_body(const float* __restrict__ xpm,
                                           const double* __restrict__ avg,
                                           const double* __restrict__ nrm,
                                           const unsigned long long* __restrict__ dmm,
                                           const float* __restrict__ gn,
                                           const void* __restrict__ gw, const void* __restrict__ gb,
                                           const void* __restrict__ b1, const void* __restrict__ b2,
                                           const unsigned short* __restrict__ wc,
                                           float* __restrict__ outp,
                                           char* __restrict__ un, unsigned short (*et)[136]) {
  double (*sdp)[9] = (double(*)[9])un;                        // [0, 18432)
  float (*wls)[9] = (float(*)[9])(un + 18432);                // [18432, 20736)
  unsigned short (*Hl)[272] = (unsigned short(*)[272])un;     // phase-2 overlay

  const int t = threadIdx.x;
  const int px = t & 63, qt = t >> 6;
  const int gp0 = blockIdx.x * 64;          // 64 | PD -> block within one batch
  const int b = gp0 / PD, p0b = gp0 - b * PD;
  const int p = p0b + px;
  const int y = p / WD, xx = p - y * WD;
  int q[9];
  neigh9(y, xx, q);

  // ---- phase 1a: fp64 partial sims, thread = (pixel px, channel quarter qt) ----
  float cv[32];
  const float* crow = xpm + (size_t)(gp0 + px) * 128 + qt * 32;
  #pragma unroll
  for (int seg = 0; seg < 8; ++seg) *(float4*)(cv + seg * 4) = *(const float4*)(crow + seg * 4);
  #pragma unroll
  for (int k = 0; k < 9; ++k) {
    const float* nrow = xpm + (size_t)(b * PD + q[k]) * 128 + qt * 32;
    double a = 0.0;
    #pragma unroll
    for (int seg = 0; seg < 8; ++seg) {
      float4 nv = *(const float4*)(nrow + seg * 4);
      a += (double)cv[seg * 4 + 0] * (double)nv.x;
      a += (double)cv[seg * 4 + 1] * (double)nv.y;
      a += (double)cv[seg * 4 + 2] * (double)nv.z;
      a += (double)cv[seg * 4 + 3] * (double)nv.w;
    }
    sdp[t][k] = a;
  }
  __syncthreads();

  // ---- phase 1b (R5-exact): one thread per pixel -> count, ranks, softmax weights ----
  if (t < 64) {
    double dmin = __longlong_as_double((long long)dmm[b]);
    double dmax = __longlong_as_double((long long)dmm[b + 8]);
    double df = lap_df(avg, b, y, xx);
    double dn = (df - dmin) / (dmax - dmin + 1e-8);
    int kk = 1 + (int)rint(dn * 7.0);
    kk = kk < 1 ? 1 : (kk > 8 ? 8 : kk);

    double np_ = fmax(nrm[b * PD + p], 1e-12);
    double s[9];
    #pragma unroll
    for (int k = 0; k < 9; ++k) {
      double sd = sdp[px][k] + sdp[px + 64][k] + sdp[px + 128][k] + sdp[px + 192][k];
      double nq = fmax(nrm[b * PD + q[k]], 1e-12);
      s[k] = sd / (np_ * nq);
    }
    float w[9];
    float wsum = 0.f;
    #pragma unroll
    for (int j = 0; j < 9; ++j) {
      int rank = 0;
      #pragma unroll
      for (int i = 0; i < 9; ++i)
        rank += (s[i] > s[j]) || (s[i] == s[j] && i < j);   // stable tie rule
      w[j] = (rank < kk) ? expf((float)s[j]) : 0.f;
      wsum += w[j];
    }
    float inv = 1.f / wsum;
    #pragma unroll
    for (int j = 0; j < 9; ++j) wls[px][j] = w[j] * inv;
  }
  __syncthreads();

  // ---- phase 1c: aggregate (vectorized, L1/L2-hot) + GroupNorm -> et (bf16) ----
  {
    float w[9];
    #pragma unroll
    for (int k = 0; k < 9; ++k) w[k] = wls[px][k];
    float og[32];
    #pragma unroll
    for (int j = 0; j < 32; ++j) og[j] = 0.f;
    #pragma unroll
    for (int k = 0; k < 9; ++k) {
      const float* nrow = xpm + (size_t)(b * PD + q[k]) * 128 + qt * 32;
      #pragma unroll
      for (int seg = 0; seg < 8; ++seg) {
        float4 nv = *(const float4*)(nrow + seg * 4);
        og[seg * 4 + 0] += w[k] * nv.x;
        og[seg * 4 + 1] += w[k] * nv.y;
        og[seg * 4 + 2] += w[k] * nv.z;
        og[seg * 4 + 3] += w[k] * nv.w;
      }
    }
    const int g16 = b * 16;
    #pragma unroll
    for (int seg = 0; seg < 4; ++seg) {
      int g = qt * 4 + seg;
      float mu = gn[g16 + g], rs = gn[128 + g16 + g];
      unsigned int pk[4];
      #pragma unroll
      for (int j = 0; j < 8; ++j) {
        int c = qt * 32 + seg * 8 + j;
        float e = og[seg * 8 + j] + (cv[seg * 8 + j] - mu) * rs * ldv<F32>(gw, c) + ldv<F32>(gb, c);
        unsigned int h = (unsigned int)f2bfu(e);
        if (j & 1) pk[j >> 1] |= h << 16;
        else pk[j >> 1] = h;
      }
      uint4 v; v.x = pk[0]; v.y = pk[1]; v.z = pk[2]; v.w = pk[3];
      *(uint4*)&et[px][qt * 32 + seg * 8] = v;
    }
  }
  __syncthreads();   // et complete; sdp/wls dead -> Hl overlay may be written

  // ---- phase 2 stage 1 (R5-exact): H[64x256] = relu(et * W1^T + b1) ----
  const unsigned short* wc1 = wc;          // w1 [256][128]
  const unsigned short* wc2 = wc + 32768;  // w2 [128][256]
  const int lane = t & 63, wave = t >> 6;
  const int r16 = lane & 15, quad = lane >> 4;
  f32x4 acc[16];
  #pragma unroll
  for (int nt = 0; nt < 16; ++nt) acc[nt] = (f32x4){0.f, 0.f, 0.f, 0.f};
  #pragma unroll
  for (int kk = 0; kk < 4; ++kk) {
    short8 af = *(const short8*)&et[wave * 16 + r16][kk * 32 + quad * 8];
    #pragma unroll
    for (int nt = 0; nt < 16; ++nt) {
      const short8* Bp = (const short8*)(wc1 + (size_t)(nt * 16 + r16) * 128 + kk * 32 + quad * 8);
      acc[nt] = __builtin_amdgcn_mfma_f32_16x16x32_bf16(af, *Bp, acc[nt], 0, 0, 0);
    }
  }
  #pragma unroll
  for (int nt = 0; nt < 16; ++nt) {
    int n = nt * 16 + r16;
    float bias = ldv<F32>(b1, n);
    #pragma unroll
    for (int r = 0; r < 4; ++r)
      Hl[wave * 16 + quad * 4 + r][n] = f2bfu(fmaxf(acc[nt][r] + bias, 0.f));
  }
  __syncthreads();

  // ---- phase 2 stage 2 (R5-exact): out = H*W2^T + b2 + et ----
  f32x4 acc2[8];
  #pragma unroll
  for (int nt = 0; nt < 8; ++nt) acc2[nt] = (f32x4){0.f, 0.f, 0.f, 0.f};
  #pragma unroll
  for (int kk = 0; kk < 8; ++kk) {
    short8 af = *(const short8*)&Hl[wave * 16 + r16][kk * 32 + quad * 8];
    #pragma unroll
    for (int nt = 0; nt < 8; ++nt) {
      const short8* Bp = (const short8*)(wc2 + (size_t)(nt * 16 + r16) * 256 + kk * 32 + quad * 8);
      acc2[nt] = __builtin_amdgcn_mfma_f32_16x16x32_bf16(af, *Bp, acc2[nt], 0, 0, 0);
    }
  }
  const int mloc0 = wave * 16 + quad * 4;
  const int pp0 = p0b + mloc0;             // % 4 == 0
  #pragma unroll
  for (int nt = 0; nt < 8; ++nt) {
    int n = nt * 16 + r16;
    float bias = ldv<F32>(b2, n);
    float4 o;
    o.x = acc2[nt][0] + bias + bfu2f(et[mloc0 + 0][n]);
    o.y = acc2[nt][1] + bias + bfu2f(et[mloc0 + 1][n]);
    o.z = acc2[nt][2] + bias + bfu2f(et[mloc0 + 2][n]);
    o.w = acc2[nt][3] + bias + bfu2f(et[mloc0 + 3][n]);
    *(float4*)(outp + (size_t)(b * CD + n) * PD + pp0) = o;
  }
}

__global__ __launch_bounds__(256, 1) void k_fused(const float* __restrict__ xpm,
                                                  const int* __restrict__ flag,
                                                  const double* __restrict__ avg,
                                                  const double* __restrict__ nrm,
                                                  const unsigned long long* __restrict__ dmm,
                                                  const float* __restrict__ gn,
                                                  const void* __restrict__ gw,
                                                  const void* __restrict__ gb,
                                                  const void* __restrict__ b1,
                                                  const void* __restrict__ b2,
                                                  const unsigned short* __restrict__ wc,
                                                  float* __restrict__ outp) {
  __shared__ char un[34816];               // union: sdp+wls | Hl
  __shared__ unsigned short et[64][136];
  if (*flag) fused_body<true>(xpm, avg, nrm, dmm, gn, gw, gb, b1, b2, wc, outp, un, et);
  else fused_body<false>(xpm, avg, nrm, dmm, gn, gw, gb, b1, b2, wc, outp, un, et);
}

extern "C" void kernel_launch(void* const* d_in, const int* in_sizes, int n_in,
                              void* d_out, int out_size, void* d_ws, size_t ws_size,
                              hipStream_t stream) {
  // dict order: x, gn_weight(128), gn_bias(128), w1(32768), b1(256), w2(32768), b2(128)
  const void* x  = d_in[0];
  const void* gw = d_in[1];
  const void* gb = d_in[2];
  const void* w1 = d_in[3];
  const void* b1 = d_in[4];
  const void* w2 = d_in[5];
  const void* b2 = d_in[6];
  float* out = (float*)d_out;

  char* ws = (char*)d_ws;
  int* flag = (int*)ws;                                      // [0,128)
  unsigned long long* dmm = (unsigned long long*)(ws + 128); // [128,256)
  float* gn = (float*)(ws + 256);                            // [256,1280)
  unsigned short* wc = (unsigned short*)(ws + 1280);         // 131072 -> 132352
  double* avg = (double*)(ws + 132352);                      // 589824 -> 722176
  double* nrm = (double*)(ws + 722176);                      // 589824 -> 1312000
  float* xpm = (float*)(ws + 1312000);                       // 37748736 -> 39060736 (~39.1 MB; R6 precedent safe)

  k_detect<<<1, 256, 0, stream>>>((const unsigned int*)x, flag);
  k_init<<<1, 64, 0, stream>>>(dmm);
  k_cvtw<<<256, 256, 0, stream>>>(w1, w2, wc, flag);
  k_pmt<<<ND / 64, 256, 0, stream>>>(x, flag, xpm);
  k_stats<<<ND / 256, 256, 0, stream>>>(x, flag, avg, nrm);
  k_minmax<<<ND / 256, 256, 0, stream>>>(avg, dmm);
  k_gn<<<BD * 16, 256, 0, stream>>>(x, flag, gn);
  k_fused<<<ND / 64, 256, 0, stream>>>(xpm, flag, avg, nrm, dmm, gn, gw, gb, b1, b2, wc, out);
}